// Round 1
// baseline (1544.647 us; speedup 1.0000x reference)
//
#include <hip/hip_runtime.h>
#include <cmath>
#include <cstdint>
#include <cstring>
#include <vector>
#include <algorithm>

#ifndef M_PI
#define M_PI 3.14159265358979323846
#endif

typedef float2 c2;
#define NLMN 5456   // sum_{l<16} (2l+1)^2
#define NLM  256    // sum_{l<16} (2l+1)

__device__ __forceinline__ c2 cmad(c2 acc, c2 a, c2 b) {
  acc.x = fmaf(a.x, b.x, fmaf(-a.y, b.y, acc.x));
  acc.y = fmaf(a.x, b.y, fmaf( a.y, b.x, acc.y));
  return acc;
}

// ---------------------------------------------------------------------------
// K1: xf1[row=(b*12+i)*64+z][m15] = (1/64) sum_a x[row][a] * e^{-2pi i a m/64}
__global__ void k_s2_fft(const float* __restrict__ x, c2* __restrict__ xf1,
                         const c2* __restrict__ dft64) {
  __shared__ float row[64];
  int r = blockIdx.x;
  row[threadIdx.x] = x[(size_t)r * 64 + threadIdx.x];
  __syncthreads();
  int m = threadIdx.x;
  if (m < 31) {
    float ax = 0.f, ay = 0.f;
    #pragma unroll
    for (int a = 0; a < 64; ++a) {
      c2 e = dft64[m * 64 + a];
      float v = row[a];
      ax = fmaf(v, e.x, ax); ay = fmaf(v, e.y, ay);
    }
    xf1[(size_t)r * 31 + m] = make_float2(ax * (1.f / 64.f), ay * (1.f / 64.f));
  }
}

// K2: wh[m15][io] = sum_j w[io][j] * tab[m15][j]
__global__ __launch_bounds__(256) void k_wfft(const float* __restrict__ w,
                       c2* __restrict__ wh, const c2* __restrict__ tab,
                       int IO, int J) {
  int t = blockIdx.x * blockDim.x + threadIdx.x;
  if (t >= 31 * IO) return;
  int m = t / IO, io = t - m * IO;
  float ax = 0.f, ay = 0.f;
  for (int j = 0; j < J; ++j) {
    float v = w[(size_t)io * J + j];
    c2 e = tab[m * J + j];
    ax = fmaf(v, e.x, ax); ay = fmaf(v, e.y, ay);
  }
  wh[t] = make_float2(ax, ay);
}

// K3: X1[lm][b*12+i] = sum_z cf1[l][m15][z] * xf1[(b*12+i)*64+z][m15]
__global__ __launch_bounds__(256) void k_X1(const c2* __restrict__ xf1,
                     c2* __restrict__ X1, const float* __restrict__ cf1,
                     const int* __restrict__ lm_l, const int* __restrict__ lm_m) {
  int t = blockIdx.x * blockDim.x + threadIdx.x;
  if (t >= NLM * 96) return;
  int lm = t / 96, bi = t - lm * 96;
  int l = lm_l[lm], m15 = lm_m[lm];
  const float* cf = cf1 + (size_t)(l * 31 + m15) * 64;
  const c2* xp = xf1 + (size_t)bi * 64 * 31 + m15;
  float ax = 0.f, ay = 0.f;
  #pragma unroll 8
  for (int z = 0; z < 64; ++z) {
    float wg = cf[z];
    c2 v = xp[(size_t)z * 31];
    ax = fmaf(wg, v.x, ax); ay = fmaf(wg, v.y, ay);
  }
  X1[t] = make_float2(ax, ay);
}

// K4: Z1[bo][lmn] = cp1[l][n15] * sum_i X1[lm][b][i] * wh1[n15][i*32+o]
__global__ __launch_bounds__(256) void k_Z1(const c2* __restrict__ X1,
                     const c2* __restrict__ wh1, c2* __restrict__ Z1,
                     const float* __restrict__ cp1,
                     const int* __restrict__ lmn_l, const int* __restrict__ lmn_m,
                     const int* __restrict__ lmn_n) {
  int t = blockIdx.x * blockDim.x + threadIdx.x;
  if (t >= 256 * NLMN) return;
  int bo = t / NLMN, lmn = t - bo * NLMN;
  int b = bo >> 5, o = bo & 31;
  int l = lmn_l[lmn], m15 = lmn_m[lmn], n15 = lmn_n[lmn];
  int lm = l * l + (m15 - 15 + l);
  float s = cp1[l * 31 + n15];
  c2 acc = make_float2(0.f, 0.f);
  const c2* xp = X1 + (size_t)(lm * 8 + b) * 12;
  const c2* wp = wh1 + (size_t)n15 * 384 + o;
  #pragma unroll
  for (int i = 0; i < 12; ++i) acc = cmad(acc, xp[i], wp[(size_t)i * 32]);
  Z1[t] = make_float2(acc.x * s, acc.y * s);
}

// K5: freq[bl][o][z][mn] = sum_{l>=lmin} cd[l][z][mn] * Z[(b0+bl)*O+o][lmn(l,m,n)]
__global__ __launch_bounds__(256) void k_scatter(const c2* __restrict__ Z,
                          c2* __restrict__ freq, const float* __restrict__ cd,
                          const int* __restrict__ base3, int O, int b0, int total) {
  int t = blockIdx.x * blockDim.x + threadIdx.x;
  if (t >= total) return;
  int mn = t % 961;
  int z = (t / 961) & 31;
  int rest = t / (961 * 32);
  int o = rest % O;
  int bl = rest / O;
  int m15 = mn / 31, n15 = mn - m15 * 31;
  int m = m15 - 15, n = n15 - 15;
  int am = m < 0 ? -m : m, an = n < 0 ? -n : n;
  int lmin = am > an ? am : an;
  const c2* Zbo = Z + (size_t)((b0 + bl) * O + o) * NLMN;
  float ax = 0.f, ay = 0.f;
  for (int l = lmin; l < 16; ++l) {
    float d = cd[(size_t)(l * 32 + z) * 961 + mn];
    int tl = 2 * l + 1;
    c2 zv = Zbo[base3[l] + (m + l) * tl + (n + l)];
    ax = fmaf(d, zv.x, ax); ay = fmaf(d, zv.y, ay);
  }
  freq[t] = make_float2(ax, ay);
}

// K6: fused 2D inverse DFT (31x31 freq -> 32x32 spatial) + bias, one image/block
__global__ __launch_bounds__(256) void k_idft2(const c2* __restrict__ freq,
                        float* __restrict__ out, const float* __restrict__ bias,
                        const c2* __restrict__ idft32, int O) {
  __shared__ c2 fq[961];
  __shared__ c2 Tm[31 * 32];
  __shared__ c2 tab[31 * 32];
  int img = blockIdx.x;  // bl*O*32 + o*32 + z
  int tid = threadIdx.x;
  const c2* f = freq + (size_t)img * 961;
  for (int k = tid; k < 961; k += 256) fq[k] = f[k];
  for (int k = tid; k < 992; k += 256) tab[k] = idft32[k];
  __syncthreads();
  {
    int mm = tid >> 4, qq = tid & 15;
    int m0 = mm, m1 = mm + 16;
    bool v1 = (m1 < 31);
    c2 a00 = make_float2(0, 0), a01 = a00, a10 = a00, a11 = a00;
    for (int n = 0; n < 31; ++n) {
      c2 f0 = fq[m0 * 31 + n];
      c2 f1 = v1 ? fq[m1 * 31 + n] : make_float2(0, 0);
      c2 t0 = tab[n * 32 + qq];
      c2 t1 = tab[n * 32 + qq + 16];
      a00 = cmad(a00, f0, t0); a01 = cmad(a01, f0, t1);
      a10 = cmad(a10, f1, t0); a11 = cmad(a11, f1, t1);
    }
    Tm[m0 * 32 + qq] = a00; Tm[m0 * 32 + qq + 16] = a01;
    if (v1) { Tm[m1 * 32 + qq] = a10; Tm[m1 * 32 + qq + 16] = a11; }
  }
  __syncthreads();
  {
    int pp = tid >> 4, qq = tid & 15;
    float r00 = 0, r01 = 0, r10 = 0, r11 = 0;
    for (int m = 0; m < 31; ++m) {
      c2 tp0 = tab[m * 32 + pp];
      c2 tp1 = tab[m * 32 + pp + 16];
      c2 q0 = Tm[m * 32 + qq];
      c2 q1 = Tm[m * 32 + qq + 16];
      r00 = fmaf(tp0.x, q0.x, fmaf(-tp0.y, q0.y, r00));
      r01 = fmaf(tp0.x, q1.x, fmaf(-tp0.y, q1.y, r01));
      r10 = fmaf(tp1.x, q0.x, fmaf(-tp1.y, q0.y, r10));
      r11 = fmaf(tp1.x, q1.x, fmaf(-tp1.y, q1.y, r11));
    }
    int o = (img / 32) % O;
    float bv = bias[o];
    float* ob = out + (size_t)img * 1024;
    ob[pp * 32 + qq] = r00 + bv;
    ob[pp * 32 + qq + 16] = r01 + bv;
    ob[(pp + 16) * 32 + qq] = r10 + bv;
    ob[(pp + 16) * 32 + qq + 16] = r11 + bv;
  }
}

// K7: G1[r][n15] = (1/32) sum_g relu(x1[r][g]) * e^{-2pi i g n/32}
__global__ __launch_bounds__(256) void k_g1(const float* __restrict__ x1,
                     c2* __restrict__ G1, const c2* __restrict__ dft32, int nrows) {
  __shared__ float rows[8][32];
  int rr = threadIdx.x >> 5, g = threadIdx.x & 31;
  int r = blockIdx.x * 8 + rr;
  float v = (r < nrows) ? x1[(size_t)r * 32 + g] : 0.f;
  rows[rr][g] = v > 0.f ? v : 0.f;
  __syncthreads();
  if (g < 31 && r < nrows) {
    float ax = 0.f, ay = 0.f;
    #pragma unroll
    for (int a = 0; a < 32; ++a) {
      float u = rows[rr][a];
      c2 e = dft32[g * 32 + a];
      ax = fmaf(u, e.x, ax); ay = fmaf(u, e.y, ay);
    }
    G1[(size_t)r * 31 + g] = make_float2(ax * (1.f / 32.f), ay * (1.f / 32.f));
  }
}

// K8: xf2[iz][m15][n15] = (1/32) sum_a e^{-2pi i a m/32} * G1[iz*32+a][n15]
__global__ __launch_bounds__(256) void k_xf2(const c2* __restrict__ G1,
                      c2* __restrict__ xf2, const c2* __restrict__ dft32, int total) {
  int t = blockIdx.x * blockDim.x + threadIdx.x;
  if (t >= total) return;
  int n15 = t % 31;
  int m15 = (t / 31) % 31;
  int iz = t / 961;
  const c2* g = G1 + (size_t)iz * 992 + n15;
  const c2* e = dft32 + m15 * 32;
  c2 acc = make_float2(0.f, 0.f);
  #pragma unroll 8
  for (int a = 0; a < 32; ++a) acc = cmad(acc, e[a], g[(size_t)a * 31]);
  xf2[t] = make_float2(acc.x * (1.f / 32.f), acc.y * (1.f / 32.f));
}

// K9: X2[((b0+bl)*32+i)][lmn] = sum_z cw2[l][z][mn] * xf2[bl][i][z][mn]
__global__ __launch_bounds__(256) void k_X2(const c2* __restrict__ xf2,
                     c2* __restrict__ X2, const float* __restrict__ cw2,
                     const int* __restrict__ lmn_l, const int* __restrict__ lmn_m,
                     const int* __restrict__ lmn_n, int b0, int total) {
  int t = blockIdx.x * blockDim.x + threadIdx.x;
  if (t >= total) return;
  int lmn = t % NLMN;
  int i = (t / NLMN) & 31;
  int bl = t / (NLMN * 32);
  int l = lmn_l[lmn], m15 = lmn_m[lmn], n15 = lmn_n[lmn];
  int mn = m15 * 31 + n15;
  const c2* xp = xf2 + (size_t)(bl * 32 + i) * 32 * 961 + mn;
  const float* cw = cw2 + (size_t)l * 32 * 961 + mn;
  float ax = 0.f, ay = 0.f;
  for (int z = 0; z < 32; ++z) {
    float wg = cw[(size_t)z * 961];
    c2 v = xp[(size_t)z * 961];
    ax = fmaf(wg, v.x, ax); ay = fmaf(wg, v.y, ay);
  }
  X2[(size_t)((b0 + bl) * 32 + i) * NLMN + lmn] = make_float2(ax, ay);
}

// K10: U[bo][lmk] = sum_i X2[b][i][lmk] * wh2[k15][i*64+o]
__global__ __launch_bounds__(256) void k_U(const c2* __restrict__ X2,
                    const c2* __restrict__ wh2, c2* __restrict__ U,
                    const int* __restrict__ lmn_n, int total) {
  int t = blockIdx.x * blockDim.x + threadIdx.x;
  if (t >= total) return;
  int lmk = t % NLMN;
  int bo = t / NLMN;
  int b = bo >> 6, o = bo & 63;
  int k15 = lmn_n[lmk];
  const c2* xp = X2 + (size_t)b * 32 * NLMN + lmk;
  const c2* wp = wh2 + (size_t)k15 * 2048 + o;
  c2 acc = make_float2(0.f, 0.f);
  #pragma unroll 8
  for (int i = 0; i < 32; ++i) acc = cmad(acc, xp[(size_t)i * NLMN], wp[(size_t)i * 64]);
  U[t] = acc;
}

// K11: Z2[bo][lmn] = sum_k U[bo][lmk] * cp2[l][k15][n15]
__global__ __launch_bounds__(256) void k_Z2(const c2* __restrict__ U,
                     c2* __restrict__ Z2, const float* __restrict__ cp2,
                     const int* __restrict__ lmn_l, const int* __restrict__ lmn_m,
                     const int* __restrict__ lmn_n, const int* __restrict__ base3,
                     int total) {
  int t = blockIdx.x * blockDim.x + threadIdx.x;
  if (t >= total) return;
  int lmn = t % NLMN;
  int bo = t / NLMN;
  int l = lmn_l[lmn], m15 = lmn_m[lmn], n15 = lmn_n[lmn];
  int tl = 2 * l + 1;
  const c2* up = U + (size_t)bo * NLMN + base3[l] + (m15 - 15 + l) * tl;
  const float* cp = cp2 + ((size_t)l * 31 + (15 - l)) * 31 + n15;
  float ax = 0.f, ay = 0.f;
  for (int kk = 0; kk < tl; ++kk) {
    float s = cp[(size_t)kk * 31];
    c2 uv = up[kk];
    ax = fmaf(s, uv.x, ax); ay = fmaf(s, uv.y, ay);
  }
  Z2[t] = make_float2(ax, ay);
}

// ---------------------------------------------------------------------------
namespace {

struct DC {
  c2 *dft64, *dft32, *idft32;
  float *cf1, *cp1, *cd1, *cw2, *cp2;
  int *base3, *lmn_l, *lmn_m, *lmn_n, *lm_l, *lm_m;
};
DC g{};
void* g_base = nullptr;
double s_fact[64];

void wig_d(int l, double beta, double* out) {
  // out[a*(2l+1)+b], m'=a-l (row), m=b-l (col); d = <m'|exp(-i beta Jy)|m>
  int n = 2 * l + 1;
  double cb = cos(beta * 0.5), sb = sin(beta * 0.5);
  for (int a = 0; a < n; ++a) {
    int mp = a - l;
    for (int b = 0; b < n; ++b) {
      int m = b - l;
      double pref = sqrt(s_fact[l + mp] * s_fact[l - mp] * s_fact[l + m] * s_fact[l - m]);
      int smin = std::max(0, m - mp);
      int smax = std::min(l + m, l - mp);
      double sum = 0.0;
      for (int s = smin; s <= smax; ++s) {
        double denom = s_fact[l + m - s] * s_fact[s] * s_fact[mp - m + s] * s_fact[l - mp - s];
        double sign = ((mp - m + s) & 1) ? -1.0 : 1.0;
        sum += sign / denom * std::pow(cb, 2 * l + m - mp - 2 * s)
                            * std::pow(sb, mp - m + 2 * s);
      }
      out[a * n + b] = pref * sum;
    }
  }
}

void quad_w(int b, double* w) {
  for (int k = 0; k < 2 * b; ++k) {
    double th = M_PI * (2.0 * k + 1.0) / (4.0 * b);
    double s = 0;
    for (int j = 0; j < b; ++j) s += sin(th * (2 * j + 1)) / (2 * j + 1);
    w[k] = 2.0 / b * sin(th) * s;
  }
}

void build_and_upload() {
  if (g_base) return;
  s_fact[0] = 1;
  for (int i = 1; i < 64; ++i) s_fact[i] = s_fact[i - 1] * i;

  size_t pos = 0;
  auto al = [&](size_t b) { pos = (pos + 15) & ~(size_t)15; size_t r = pos; pos += b; return r; };
  size_t o_dft64 = al(31 * 64 * sizeof(c2));
  size_t o_dft32 = al(31 * 32 * sizeof(c2));
  size_t o_idft32 = al(31 * 32 * sizeof(c2));
  size_t o_cf1 = al(16 * 31 * 64 * 4);
  size_t o_cp1 = al(16 * 31 * 4);
  size_t o_cd1 = al((size_t)16 * 32 * 961 * 4);
  size_t o_cw2 = al((size_t)16 * 32 * 961 * 4);
  size_t o_cp2 = al((size_t)16 * 961 * 4);
  size_t o_b3 = al(16 * 4);
  size_t o_ll = al(NLMN * 4), o_lm_ = al(NLMN * 4), o_ln = al(NLMN * 4);
  size_t o_lml = al(NLM * 4), o_lmm = al(NLM * 4);
  size_t total = pos;
  std::vector<char> blob(total, 0);

  c2* dft64 = (c2*)(blob.data() + o_dft64);
  for (int m15 = 0; m15 < 31; ++m15) {
    int m = m15 - 15;
    for (int a = 0; a < 64; ++a) {
      double ang = -2.0 * M_PI * a * m / 64.0;
      dft64[m15 * 64 + a] = make_float2((float)cos(ang), (float)sin(ang));
    }
  }
  c2* dft32 = (c2*)(blob.data() + o_dft32);
  c2* idft32 = (c2*)(blob.data() + o_idft32);
  for (int m15 = 0; m15 < 31; ++m15) {
    int m = m15 - 15;
    for (int a = 0; a < 32; ++a) {
      double ang = -2.0 * M_PI * a * m / 32.0;
      dft32[m15 * 32 + a] = make_float2((float)cos(ang), (float)sin(ang));
      double angi = 2.0 * M_PI * a * m / 32.0;  // a plays role of p
      idft32[m15 * 32 + a] = make_float2((float)cos(angi), (float)sin(angi));
    }
  }

  const double S2S = 1.0 / sqrt(768.0);    // 1/sqrt(2*32*12)
  const double SO3S = 1.0 / sqrt(1024.0);  // 1/sqrt(2*16*32)
  double qw32[64], qw16[32], beta32[64], beta16[32];
  quad_w(32, qw32);
  quad_w(16, qw16);
  for (int k = 0; k < 64; ++k) beta32[k] = M_PI * (2 * k + 1) / 128.0;
  for (int k = 0; k < 32; ++k) beta16[k] = M_PI * (2 * k + 1) / 64.0;

  float* cf1 = (float*)(blob.data() + o_cf1);
  float* cp1 = (float*)(blob.data() + o_cp1);
  float* cd1 = (float*)(blob.data() + o_cd1);
  float* cw2 = (float*)(blob.data() + o_cw2);
  float* cp2 = (float*)(blob.data() + o_cp2);
  std::vector<double> dbuf(31 * 31);

  for (int l = 0; l < 16; ++l) {
    int tl = 2 * l + 1;
    for (int z = 0; z < 64; ++z) {
      wig_d(l, beta32[z], dbuf.data());
      for (int m = -l; m <= l; ++m)
        cf1[(size_t)(l * 31 + (m + 15)) * 64 + z] = (float)(qw32[z] * dbuf[(m + l) * tl + l]);
    }
    wig_d(l, M_PI / 2, dbuf.data());
    for (int n = -l; n <= l; ++n)
      cp1[l * 31 + (n + 15)] = (float)(S2S * dbuf[(n + l) * tl + l]);
    for (int k = -l; k <= l; ++k)
      for (int n = -l; n <= l; ++n)
        cp2[((size_t)l * 31 + (k + 15)) * 31 + (n + 15)] = (float)(SO3S * dbuf[(k + l) * tl + (n + l)]);
    for (int z = 0; z < 32; ++z) {
      wig_d(l, beta16[z], dbuf.data());
      for (int m = -l; m <= l; ++m)
        for (int n = -l; n <= l; ++n) {
          double d = dbuf[(m + l) * tl + (n + l)];
          size_t idx = (size_t)(l * 32 + z) * 961 + (m + 15) * 31 + (n + 15);
          cd1[idx] = (float)((2 * l + 1) * d);  // shared: b_out=16 for both convs
          cw2[idx] = (float)(qw16[z] * d);
        }
    }
  }

  int* b3 = (int*)(blob.data() + o_b3);
  int* ll = (int*)(blob.data() + o_ll);
  int* lmv = (int*)(blob.data() + o_lm_);
  int* ln = (int*)(blob.data() + o_ln);
  int* lml = (int*)(blob.data() + o_lml);
  int* lmm = (int*)(blob.data() + o_lmm);
  int idx = 0;
  for (int l = 0; l < 16; ++l) {
    b3[l] = idx;
    for (int a = 0; a < 2 * l + 1; ++a)
      for (int c = 0; c < 2 * l + 1; ++c) {
        ll[idx] = l; lmv[idx] = (a - l) + 15; ln[idx] = (c - l) + 15; ++idx;
      }
  }
  int idx2 = 0;
  for (int l = 0; l < 16; ++l)
    for (int a = 0; a < 2 * l + 1; ++a) { lml[idx2] = l; lmm[idx2] = (a - l) + 15; ++idx2; }

  void* dev = nullptr;
  if (hipMalloc(&dev, total) != hipSuccess) return;
  if (hipMemcpy(dev, blob.data(), total, hipMemcpyHostToDevice) != hipSuccess) return;
  char* base = (char*)dev;
  g.dft64 = (c2*)(base + o_dft64);
  g.dft32 = (c2*)(base + o_dft32);
  g.idft32 = (c2*)(base + o_idft32);
  g.cf1 = (float*)(base + o_cf1);
  g.cp1 = (float*)(base + o_cp1);
  g.cd1 = (float*)(base + o_cd1);
  g.cw2 = (float*)(base + o_cw2);
  g.cp2 = (float*)(base + o_cp2);
  g.base3 = (int*)(base + o_b3);
  g.lmn_l = (int*)(base + o_ll);
  g.lmn_m = (int*)(base + o_lm_);
  g.lmn_n = (int*)(base + o_ln);
  g.lm_l = (int*)(base + o_lml);
  g.lm_m = (int*)(base + o_lmm);
  g_base = dev;
}

struct Boot { Boot() { build_and_upload(); } };
Boot s_boot;

}  // namespace

// ---------------------------------------------------------------------------
extern "C" void kernel_launch(void* const* d_in, const int* in_sizes, int n_in,
                              void* d_out, int out_size, void* d_ws, size_t ws_size,
                              hipStream_t stream) {
  (void)in_sizes; (void)n_in; (void)out_size;
  if (!g_base) build_and_upload();  // normally done in static ctor (pre-capture)

  const float* x = (const float*)d_in[0];
  const float* w_s2 = (const float*)d_in[1];
  const float* b_s2 = (const float*)d_in[2];
  const float* w_so3 = (const float*)d_in[3];
  const float* b_so3 = (const float*)d_in[4];
  float* out = (float*)d_out;
  c2* W = (c2*)d_ws;
  size_t cap = ws_size / sizeof(c2);

  // ---------------- S2 conv ----------------
  {
    c2* xf1 = W;                  // 190464
    c2* wh1 = W + 190464;         // 11904
    c2* X1  = W + 202368;         // 24576
    c2* Z1  = W + 226944;         // 1396736
    c2* fq  = W + 1623680;        // bch * 984064
    int bch = 8;
    while (bch > 1 && 1623680ull + (size_t)bch * 984064 > cap) bch >>= 1;

    k_s2_fft<<<dim3(6144), dim3(64), 0, stream>>>(x, xf1, g.dft64);
    k_wfft<<<dim3((31 * 384 + 255) / 256), dim3(256), 0, stream>>>(w_s2, wh1, g.dft64, 384, 64);
    k_X1<<<dim3((NLM * 96 + 255) / 256), dim3(256), 0, stream>>>(xf1, X1, g.cf1, g.lm_l, g.lm_m);
    k_Z1<<<dim3((256 * NLMN + 255) / 256), dim3(256), 0, stream>>>(X1, wh1, Z1, g.cp1,
                                                                   g.lmn_l, g.lmn_m, g.lmn_n);
    for (int b0 = 0; b0 < 8; b0 += bch) {
      int tot = bch * 32 * 32 * 961;
      k_scatter<<<dim3((tot + 255) / 256), dim3(256), 0, stream>>>(Z1, fq, g.cd1, g.base3, 32, b0, tot);
      k_idft2<<<dim3(bch * 32 * 32), dim3(256), 0, stream>>>(fq, out + (size_t)b0 * 1048576,
                                                             b_s2, g.idft32, 32);
    }
  }

  // ---------------- SO3 conv ----------------
  {
    c2* X2 = W;                   // 1396736
    c2* wh2 = W + 1396736;        // 63488
    const size_t o_front = 1460224;
    c2* U  = W + 1460224;         // 2793472
    c2* Z2 = W + 4253696;         // 2793472
    c2* fq2 = W + 7047168;        // bchT * 1968128
    int bchF = 8;
    while (bchF > 1 && o_front + (size_t)bchF * (1015808 + 984064) > cap) bchF >>= 1;
    int bchT = 8;
    while (bchT > 1 && 7047168ull + (size_t)bchT * 1968128 > cap) bchT >>= 1;

    k_wfft<<<dim3((31 * 2048 + 255) / 256), dim3(256), 0, stream>>>(w_so3, wh2, g.dft32, 2048, 32);

    for (int b0 = 0; b0 < 8; b0 += bchF) {
      c2* G1 = W + o_front;
      c2* xf2 = G1 + (size_t)bchF * 1015808;
      int rows = bchF * 32768;
      k_g1<<<dim3(rows / 8), dim3(256), 0, stream>>>(out + (size_t)b0 * 1048576, G1, g.dft32, rows);
      int t2 = bchF * 984064;
      k_xf2<<<dim3((t2 + 255) / 256), dim3(256), 0, stream>>>(G1, xf2, g.dft32, t2);
      int t3 = bchF * 32 * NLMN;
      k_X2<<<dim3((t3 + 255) / 256), dim3(256), 0, stream>>>(xf2, X2, g.cw2,
                                                             g.lmn_l, g.lmn_m, g.lmn_n, b0, t3);
    }

    int tU = 512 * NLMN;
    k_U<<<dim3((tU + 255) / 256), dim3(256), 0, stream>>>(X2, wh2, U, g.lmn_n, tU);
    k_Z2<<<dim3((tU + 255) / 256), dim3(256), 0, stream>>>(U, Z2, g.cp2,
                                                           g.lmn_l, g.lmn_m, g.lmn_n, g.base3, tU);

    for (int b0 = 0; b0 < 8; b0 += bchT) {
      int tot = bchT * 64 * 32 * 961;
      k_scatter<<<dim3((tot + 255) / 256), dim3(256), 0, stream>>>(Z2, fq2, g.cd1, g.base3, 64, b0, tot);
      k_idft2<<<dim3(bchT * 64 * 32), dim3(256), 0, stream>>>(fq2, out + 8388608 + (size_t)b0 * 2097152,
                                                              b_so3, g.idft32, 64);
    }
  }
}